// Round 1
// baseline (64.027 us; speedup 1.0000x reference)
//
#include <hip/hip_runtime.h>

#define BB 16
#define NN 128
#define DD 128

// Kernel 1: es[b,j,d] = sum_i adj[b,i,j] * e[b,i,j,d]
// One block per (b,j). 256 threads: lane d4 = t&31 (float4 column), ig = t>>5
// owns 16 of the 128 i-rows. Loads predicated on adj!=0 (about half are zero)
// so the HW skips those 512B row segments entirely.
__global__ __launch_bounds__(256) void es_kernel(const float* __restrict__ e,
                                                 const float* __restrict__ adj,
                                                 float* __restrict__ es) {
    const int bj = blockIdx.x;          // b*128 + j
    const int b = bj >> 7, j = bj & 127;
    const int t = threadIdx.x;
    __shared__ float adj_s[NN];
    __shared__ float4 red[8][32];
    if (t < NN) adj_s[t] = adj[(size_t)(b * NN + t) * NN + j];
    __syncthreads();
    const int d4 = t & 31, ig = t >> 5;
    const float4* e4 = (const float4*)e;
    float4 acc = make_float4(0.f, 0.f, 0.f, 0.f);
    #pragma unroll
    for (int ii = 0; ii < 16; ++ii) {
        const int i = ig * 16 + ii;
        const float a = adj_s[i];
        if (a != 0.0f) {
            float4 v = e4[(size_t)((b * NN + i) * NN + j) * 32 + d4];
            acc.x += a * v.x; acc.y += a * v.y;
            acc.z += a * v.z; acc.w += a * v.w;
        }
    }
    red[ig][d4] = acc;
    __syncthreads();
    if (t < 32) {
        float4 s = red[0][t];
        #pragma unroll
        for (int r = 1; r < 8; ++r) {
            float4 v = red[r][t];
            s.x += v.x; s.y += v.y; s.z += v.z; s.w += v.w;
        }
        ((float4*)es)[(size_t)bj * 32 + t] = s;
    }
}

// Kernel 2: everything else, fused. One block per (b, jtile of 8).
// msum[b,j,k] = ah[b,j,:]·W1[k,:] + deg[b,j]*(h[b,j,:]·W2[k,:] + bm[k]) + es[b,j,:]·W3[k,:]
// out[b,j,k]  = h[b,j,:]·WuA[k,:] + msum[b,j,:]·WuB[k,:] + bu[k]
// where ah[b,j,d] = sum_i adj[b,i,j]*h[b,i,d], deg[b,j] = sum_i adj[b,i,j].
__global__ __launch_bounds__(256) void fuse_kernel(
    const float* __restrict__ h, const float* __restrict__ adj,
    const float* __restrict__ es, const float* __restrict__ Wm,
    const float* __restrict__ bm, const float* __restrict__ Wu,
    const float* __restrict__ bu, float* __restrict__ out) {
    const int blk = blockIdx.x;
    const int b = blk >> 4;
    const int jbase = (blk & 15) * 8;
    const int t = threadIdx.x;
    __shared__ float h_s[8][DD];
    __shared__ float es_s[8][DD];
    __shared__ float ah_s[8][DD];
    __shared__ float ms_s[8][DD];
    __shared__ float adj_s[8][NN];   // [jj][i]
    __shared__ float deg_s[8];

    // stage h, es rows (coalesced) and the 8 adj columns
    for (int x = t; x < 1024; x += 256) {
        const int jj = x >> 7, d0 = x & 127;
        h_s[jj][d0]  = h [(size_t)(b * NN + jbase + jj) * DD + d0];
        es_s[jj][d0] = es[(size_t)(b * NN + jbase + jj) * DD + d0];
        const int i = x >> 3, j2 = x & 7;
        adj_s[j2][i] = adj[(size_t)(b * NN + i) * NN + jbase + j2];
    }
    __syncthreads();
    if (t < 8) {
        float s = 0.f;
        for (int i = 0; i < NN; ++i) s += adj_s[t][i];
        deg_s[t] = s;                 // consumed after the next barrier
    }

    const int k  = t & 127;           // output column; also 'd' in ah phase
    const int jl = t >> 7;            // 0 or 1; thread owns j = jl, jl+2, jl+4, jl+6

    // ah[b,jbase+j, d=k] for 4 j's; h reads coalesced across threads
    float a0 = 0, a1 = 0, a2 = 0, a3 = 0;
    for (int i = 0; i < NN; ++i) {
        const float hv = h[(size_t)(b * NN + i) * DD + k];
        a0 += adj_s[jl + 0][i] * hv;
        a1 += adj_s[jl + 2][i] * hv;
        a2 += adj_s[jl + 4][i] * hv;
        a3 += adj_s[jl + 6][i] * hv;
    }
    ah_s[jl + 0][k] = a0; ah_s[jl + 2][k] = a1;
    ah_s[jl + 4][k] = a2; ah_s[jl + 6][k] = a3;
    __syncthreads();

    // msum dots: thread k walks rows k of W1/W2/W3 (L2-resident)
    float pa0 = 0, pa1 = 0, pa2 = 0, pa3 = 0;   // ah·W1 + es·W3
    float ph0 = 0, ph1 = 0, ph2 = 0, ph3 = 0;   // h·W2
    const float* w1p = Wm + (size_t)k * 384;
    const float* w2p = w1p + 128;
    const float* w3p = w1p + 256;
    for (int d0 = 0; d0 < DD; ++d0) {
        const float w1 = w1p[d0], w2 = w2p[d0], w3 = w3p[d0];
        pa0 += ah_s[jl + 0][d0] * w1 + es_s[jl + 0][d0] * w3;
        pa1 += ah_s[jl + 2][d0] * w1 + es_s[jl + 2][d0] * w3;
        pa2 += ah_s[jl + 4][d0] * w1 + es_s[jl + 4][d0] * w3;
        pa3 += ah_s[jl + 6][d0] * w1 + es_s[jl + 6][d0] * w3;
        ph0 += h_s[jl + 0][d0] * w2;
        ph1 += h_s[jl + 2][d0] * w2;
        ph2 += h_s[jl + 4][d0] * w2;
        ph3 += h_s[jl + 6][d0] * w2;
    }
    const float bmk = bm[k];
    ms_s[jl + 0][k] = pa0 + deg_s[jl + 0] * (ph0 + bmk);
    ms_s[jl + 2][k] = pa1 + deg_s[jl + 2] * (ph1 + bmk);
    ms_s[jl + 4][k] = pa2 + deg_s[jl + 4] * (ph2 + bmk);
    ms_s[jl + 6][k] = pa3 + deg_s[jl + 6] * (ph3 + bmk);
    __syncthreads();

    // out = h·WuA + msum·WuB + bu
    float o0 = 0, o1 = 0, o2 = 0, o3 = 0;
    const float* wap = Wu + (size_t)k * 256;
    const float* wbp = wap + 128;
    for (int d0 = 0; d0 < DD; ++d0) {
        const float wa = wap[d0], wb = wbp[d0];
        o0 += h_s[jl + 0][d0] * wa + ms_s[jl + 0][d0] * wb;
        o1 += h_s[jl + 2][d0] * wa + ms_s[jl + 2][d0] * wb;
        o2 += h_s[jl + 4][d0] * wa + ms_s[jl + 4][d0] * wb;
        o3 += h_s[jl + 6][d0] * wa + ms_s[jl + 6][d0] * wb;
    }
    const float buk = bu[k];
    out[(size_t)(b * NN + jbase + jl + 0) * DD + k] = o0 + buk;
    out[(size_t)(b * NN + jbase + jl + 2) * DD + k] = o1 + buk;
    out[(size_t)(b * NN + jbase + jl + 4) * DD + k] = o2 + buk;
    out[(size_t)(b * NN + jbase + jl + 6) * DD + k] = o3 + buk;
}

extern "C" void kernel_launch(void* const* d_in, const int* in_sizes, int n_in,
                              void* d_out, int out_size, void* d_ws, size_t ws_size,
                              hipStream_t stream) {
    const float* h   = (const float*)d_in[0];
    const float* adj = (const float*)d_in[1];
    const float* e   = (const float*)d_in[2];
    const float* Wm  = (const float*)d_in[3];
    const float* bm  = (const float*)d_in[4];
    const float* Wu  = (const float*)d_in[5];
    const float* bu  = (const float*)d_in[6];
    float* out = (float*)d_out;
    float* es  = (float*)d_ws;   // B*N*D floats = 1 MiB scratch, fully overwritten

    es_kernel<<<BB * NN, 256, 0, stream>>>(e, adj, es);
    fuse_kernel<<<BB * (NN / 8), 256, 0, stream>>>(h, adj, es, Wm, bm, Wu, bu, out);
}

// Round 3
// 55.816 us; speedup vs baseline: 1.1471x; 1.1471x over previous
//
#include <hip/hip_runtime.h>

#define BB 16
#define NN 128
#define DD 128

// Kernel 1: es[b,j,d] = sum_i adj[b,i,j] * e[b,i,j,d]   (es lives in d_out!)
// One block per (b,j). 256 threads: lane d4 = t&31 (float4 column), ig = t>>5
// owns 16 of the 128 i-rows. Loads predicated on adj!=0 (~half are zero).
// Side job: first 320 blocks also write WmT/WuT (weight transposes) into ws,
// consumed by fuse_kernel (stream-ordered after this kernel).
__global__ __launch_bounds__(256) void es_kernel(const float* __restrict__ e,
                                                 const float* __restrict__ adj,
                                                 float* __restrict__ es,
                                                 const float* __restrict__ Wm,
                                                 const float* __restrict__ Wu,
                                                 float* __restrict__ WmT,
                                                 float* __restrict__ WuT) {
    const int bj = blockIdx.x;          // b*128 + j
    const int t = threadIdx.x;

    if (bj < 320) {                     // transpose side-job: 320*256 = 81920 = 384*128 + 256*128
        const int idx = bj * 256 + t;
        if (idx < 384 * 128) {
            WmT[idx] = Wm[(idx & 127) * 384 + (idx >> 7)];
        } else {
            const int o = idx - 384 * 128;
            WuT[o] = Wu[(o & 127) * 256 + (o >> 7)];
        }
    }

    const int b = bj >> 7, j = bj & 127;
    __shared__ float adj_s[NN];
    __shared__ float4 red[8][32];
    if (t < NN) adj_s[t] = adj[(size_t)(b * NN + t) * NN + j];
    __syncthreads();
    const int d4 = t & 31, ig = t >> 5;
    const float4* e4 = (const float4*)e;
    float4 acc = make_float4(0.f, 0.f, 0.f, 0.f);
    #pragma unroll
    for (int ii = 0; ii < 16; ++ii) {
        const int i = ig * 16 + ii;
        const float a = adj_s[i];
        if (a != 0.0f) {
            float4 v = e4[(size_t)((b * NN + i) * NN + j) * 32 + d4];
            acc.x += a * v.x; acc.y += a * v.y;
            acc.z += a * v.z; acc.w += a * v.w;
        }
    }
    red[ig][d4] = acc;
    __syncthreads();
    if (t < 32) {
        float4 s = red[0][t];
        #pragma unroll
        for (int r = 1; r < 8; ++r) {
            float4 v = red[r][t];
            s.x += v.x; s.y += v.y; s.z += v.z; s.w += v.w;
        }
        ((float4*)es)[(size_t)bj * 32 + t] = s;
    }
}

// Kernel 2: everything else, fused. One block per (b, jtile of 8).
// msum[b,j,k] = ah[b,j,:]·W1[k,:] + deg[b,j]*(h[b,j,:]·W2[k,:] + bm[k]) + es[b,j,:]·W3[k,:]
// out[b,j,k]  = h[b,j,:]·WuA[k,:] + msum[b,j,:]·WuB[k,:] + bu[k]
// Weight reads go through WmT/WuT so lanes (k consecutive) are coalesced.
// es is read from d_out; each block reads ONLY the rows it later overwrites.
__global__ __launch_bounds__(256) void fuse_kernel(
    const float* __restrict__ h, const float* __restrict__ adj,
    const float* __restrict__ es, const float* __restrict__ WmT,
    const float* __restrict__ bm, const float* __restrict__ WuT,
    const float* __restrict__ bu, float* __restrict__ out) {
    const int blk = blockIdx.x;
    const int b = blk >> 4;
    const int jbase = (blk & 15) * 8;
    const int t = threadIdx.x;
    __shared__ float h_s[8][DD];
    __shared__ float es_s[8][DD];
    __shared__ float ah_s[8][DD];
    __shared__ float ms_s[8][DD];
    __shared__ float adj_s[8][NN];   // [jj][i]
    __shared__ float deg_s[8];

    // stage h, es rows (coalesced) and the 8 adj columns
    for (int x = t; x < 1024; x += 256) {
        const int jj = x >> 7, d0 = x & 127;
        h_s[jj][d0]  = h [(size_t)(b * NN + jbase + jj) * DD + d0];
        es_s[jj][d0] = es[(size_t)(b * NN + jbase + jj) * DD + d0];
        const int i = x >> 3, j2 = x & 7;
        adj_s[j2][i] = adj[(size_t)(b * NN + i) * NN + jbase + j2];
    }
    __syncthreads();
    if (t < 8) {
        float s = 0.f;
        for (int i = 0; i < NN; ++i) s += adj_s[t][i];
        deg_s[t] = s;                 // consumed after the next barrier
    }

    const int k  = t & 127;           // output column; also 'd' in ah phase
    const int jl = t >> 7;            // 0 or 1; thread owns j = jl, jl+2, jl+4, jl+6

    // ah[b,jbase+j, d=k] for 4 j's; h reads coalesced across threads
    float a0 = 0, a1 = 0, a2 = 0, a3 = 0;
    for (int i = 0; i < NN; ++i) {
        const float hv = h[(size_t)(b * NN + i) * DD + k];
        a0 += adj_s[jl + 0][i] * hv;
        a1 += adj_s[jl + 2][i] * hv;
        a2 += adj_s[jl + 4][i] * hv;
        a3 += adj_s[jl + 6][i] * hv;
    }
    ah_s[jl + 0][k] = a0; ah_s[jl + 2][k] = a1;
    ah_s[jl + 4][k] = a2; ah_s[jl + 6][k] = a3;
    __syncthreads();

    // msum dots: weight reads coalesced via WmT (lanes k consecutive)
    float pa0 = 0, pa1 = 0, pa2 = 0, pa3 = 0;   // ah·W1 + es·W3
    float ph0 = 0, ph1 = 0, ph2 = 0, ph3 = 0;   // h·W2
    for (int d0 = 0; d0 < DD; ++d0) {
        const float w1 = WmT[(size_t)d0 * 128 + k];
        const float w2 = WmT[(size_t)(128 + d0) * 128 + k];
        const float w3 = WmT[(size_t)(256 + d0) * 128 + k];
        pa0 += ah_s[jl + 0][d0] * w1 + es_s[jl + 0][d0] * w3;
        pa1 += ah_s[jl + 2][d0] * w1 + es_s[jl + 2][d0] * w3;
        pa2 += ah_s[jl + 4][d0] * w1 + es_s[jl + 4][d0] * w3;
        pa3 += ah_s[jl + 6][d0] * w1 + es_s[jl + 6][d0] * w3;
        ph0 += h_s[jl + 0][d0] * w2;
        ph1 += h_s[jl + 2][d0] * w2;
        ph2 += h_s[jl + 4][d0] * w2;
        ph3 += h_s[jl + 6][d0] * w2;
    }
    const float bmk = bm[k];
    ms_s[jl + 0][k] = pa0 + deg_s[jl + 0] * (ph0 + bmk);
    ms_s[jl + 2][k] = pa1 + deg_s[jl + 2] * (ph1 + bmk);
    ms_s[jl + 4][k] = pa2 + deg_s[jl + 4] * (ph2 + bmk);
    ms_s[jl + 6][k] = pa3 + deg_s[jl + 6] * (ph3 + bmk);
    __syncthreads();

    // out = h·WuA + msum·WuB + bu (coalesced via WuT)
    float o0 = 0, o1 = 0, o2 = 0, o3 = 0;
    for (int d0 = 0; d0 < DD; ++d0) {
        const float wa = WuT[(size_t)d0 * 128 + k];
        const float wb = WuT[(size_t)(128 + d0) * 128 + k];
        o0 += h_s[jl + 0][d0] * wa + ms_s[jl + 0][d0] * wb;
        o1 += h_s[jl + 2][d0] * wa + ms_s[jl + 2][d0] * wb;
        o2 += h_s[jl + 4][d0] * wa + ms_s[jl + 4][d0] * wb;
        o3 += h_s[jl + 6][d0] * wa + ms_s[jl + 6][d0] * wb;
    }
    const float buk = bu[k];
    out[(size_t)(b * NN + jbase + jl + 0) * DD + k] = o0 + buk;
    out[(size_t)(b * NN + jbase + jl + 2) * DD + k] = o1 + buk;
    out[(size_t)(b * NN + jbase + jl + 4) * DD + k] = o2 + buk;
    out[(size_t)(b * NN + jbase + jl + 6) * DD + k] = o3 + buk;
}

extern "C" void kernel_launch(void* const* d_in, const int* in_sizes, int n_in,
                              void* d_out, int out_size, void* d_ws, size_t ws_size,
                              hipStream_t stream) {
    const float* h   = (const float*)d_in[0];
    const float* adj = (const float*)d_in[1];
    const float* e   = (const float*)d_in[2];
    const float* Wm  = (const float*)d_in[3];
    const float* bm  = (const float*)d_in[4];
    const float* Wu  = (const float*)d_in[5];
    const float* bu  = (const float*)d_in[6];
    float* out = (float*)d_out;
    float* es  = (float*)d_out;                // es scratch aliases d_out:
                                               // fuse block reads only the rows it overwrites
    float* WmT = (float*)d_ws;                 // 384*128 floats
    float* WuT = WmT + 384 * 128;              // 256*128 floats (320 KB total, < R1-proven 1 MiB)

    es_kernel<<<BB * NN, 256, 0, stream>>>(e, adj, es, Wm, Wu, WmT, WuT);
    fuse_kernel<<<BB * (NN / 8), 256, 0, stream>>>(h, adj, es, WmT, bm, WuT, bu, out);
}

// Round 4
// 44.509 us; speedup vs baseline: 1.4385x; 1.2540x over previous
//
#include <hip/hip_runtime.h>

#define BB 16
#define NN 128
#define DD 128

// Transpose weights into float4-interleaved layout:
// WmT4[((dcol>>2)*128 + k)*4 + (dcol&3)] = Wm[k*384 + dcol]   (384 d-rows)
// WuT4 same with 256 d-rows. Thread k then loads 4 consecutive-d weights
// as ONE float4, coalesced across lanes (16 B/lane).
__global__ __launch_bounds__(256) void wtrans_kernel(const float* __restrict__ Wm,
                                                     const float* __restrict__ Wu,
                                                     float* __restrict__ WmT4,
                                                     float* __restrict__ WuT4) {
    const int idx = blockIdx.x * 256 + threadIdx.x;   // 0..81919, coalesced reads
    if (idx < 384 * 128) {
        const int k = idx / 384, dcol = idx % 384;
        WmT4[((dcol >> 2) * 128 + k) * 4 + (dcol & 3)] = Wm[idx];
    } else {
        const int o = idx - 384 * 128;                // 0..32767
        const int k = o / 256, dcol = o % 256;
        WuT4[((dcol >> 2) * 128 + k) * 4 + (dcol & 3)] = Wu[o];
    }
}

// One fused kernel. Block = (b, 4 consecutive j's), 256 threads, 512 blocks.
// es stays in LDS; no global scratch, no inter-kernel dependency on e-path.
__global__ __launch_bounds__(256) void mpnn_kernel(
    const float* __restrict__ h, const float* __restrict__ adj,
    const float* __restrict__ e, const float* __restrict__ WmT4,
    const float* __restrict__ bm, const float* __restrict__ WuT4,
    const float* __restrict__ bu, float* __restrict__ out) {
    const int blk = blockIdx.x;
    const int b = blk >> 5;
    const int jbase = (blk & 31) * 4;
    const int t = threadIdx.x;

    __shared__ float adj_s[4][NN];
    __shared__ float h_s[4][DD];
    __shared__ float4 red[8][32];
    __shared__ float es_s[4][DD];
    __shared__ float ah_s[4][DD];
    __shared__ float ms_s[4][DD];
    __shared__ float deg_s[4];

    // ---- A: stage adj columns (gather, small) + h rows (coalesced) ----
    for (int x = t; x < 4 * NN; x += 256) {
        const int i = x >> 2, jj = x & 3;
        adj_s[jj][i] = adj[(size_t)(b * NN + i) * NN + jbase + jj];
    }
    for (int x = t; x < 4 * DD; x += 256) {
        const int jj = x >> 7, d0 = x & 127;
        h_s[jj][d0] = h[(size_t)(b * NN + jbase + jj) * DD + d0];
    }
    __syncthreads();

    // deg[jj] = sum_i adj[i][jj]  (threads 0..127, shfl within 32-lane groups)
    if (t < 128) {
        const int jj = t >> 5, l = t & 31;
        float s = adj_s[jj][l] + adj_s[jj][l + 32] + adj_s[jj][l + 64] + adj_s[jj][l + 96];
        #pragma unroll
        for (int off = 16; off; off >>= 1) s += __shfl_xor(s, off);
        if (l == 0) deg_s[jj] = s;
    }

    // ---- B: stream e (predicated). Group g of 32 lanes: jj = g&3, i-half = g>>2.
    {
        const int g = t >> 5, d4 = t & 31;
        const int jjB = g & 3, ih = g >> 2;
        const float4* __restrict__ e4 =
            (const float4*)e + ((size_t)b * NN * NN + (jbase + jjB)) * 32 + d4;
        float4 acc = make_float4(0.f, 0.f, 0.f, 0.f);
        const int i0 = ih * 64;
        #pragma unroll 4
        for (int ii = 0; ii < 64; ++ii) {
            const int i = i0 + ii;
            const float a = adj_s[jjB][i];
            if (a != 0.0f) {
                float4 v = e4[(size_t)i * (NN * 32)];
                acc.x += a * v.x; acc.y += a * v.y;
                acc.z += a * v.z; acc.w += a * v.w;
            }
        }
        red[g][d4] = acc;
    }

    // ---- C: ah[jj][k] = sum_i adj[i][jj] * h[b,i,k]  (coalesced global h) ----
    const int k = t & 127, jl = t >> 7;
    {
        float a0 = 0.f, a1 = 0.f;
        const float* __restrict__ hp = h + (size_t)b * NN * DD + k;
        for (int i = 0; i < NN; ++i) {
            const float hv = hp[(size_t)i * DD];
            a0 += adj_s[jl][i] * hv;
            a1 += adj_s[jl + 2][i] * hv;
        }
        ah_s[jl][k] = a0;
        ah_s[jl + 2][k] = a1;
    }
    __syncthreads();

    // reduce red -> es_s (threads 0..127, float4)
    if (t < 128) {
        const int jj = t >> 5, l = t & 31;
        const float4 x = red[jj][l], y = red[jj + 4][l];
        float4 s = make_float4(x.x + y.x, x.y + y.y, x.z + y.z, x.w + y.w);
        *(float4*)&es_s[jj][4 * l] = s;
    }
    __syncthreads();

    // ---- D: msum[jj][k] for jj = jl, jl+2; vectorized weight + LDS reads ----
    {
        float pa0 = 0, pa1 = 0, ph0 = 0, ph1 = 0, pe0 = 0, pe1 = 0;
        const float4* __restrict__ w1p = (const float4*)WmT4 + k;          // d-block stride 128
        const float4* __restrict__ w2p = w1p + 32 * 128;                    // dcol = 128+d0
        const float4* __restrict__ w3p = w1p + 64 * 128;                    // dcol = 256+d0
        for (int q = 0; q < 32; ++q) {                                      // d0 = 4q
            const float4 w1 = w1p[q * 128];
            const float4 w2 = w2p[q * 128];
            const float4 w3 = w3p[q * 128];
            const float4 ahA = *(const float4*)&ah_s[jl][4 * q];
            const float4 ahB = *(const float4*)&ah_s[jl + 2][4 * q];
            const float4 hA  = *(const float4*)&h_s[jl][4 * q];
            const float4 hB  = *(const float4*)&h_s[jl + 2][4 * q];
            const float4 eA  = *(const float4*)&es_s[jl][4 * q];
            const float4 eB  = *(const float4*)&es_s[jl + 2][4 * q];
            pa0 += ahA.x * w1.x + ahA.y * w1.y + ahA.z * w1.z + ahA.w * w1.w;
            pa1 += ahB.x * w1.x + ahB.y * w1.y + ahB.z * w1.z + ahB.w * w1.w;
            ph0 += hA.x * w2.x + hA.y * w2.y + hA.z * w2.z + hA.w * w2.w;
            ph1 += hB.x * w2.x + hB.y * w2.y + hB.z * w2.z + hB.w * w2.w;
            pe0 += eA.x * w3.x + eA.y * w3.y + eA.z * w3.z + eA.w * w3.w;
            pe1 += eB.x * w3.x + eB.y * w3.y + eB.z * w3.z + eB.w * w3.w;
        }
        const float bmk = bm[k];
        ms_s[jl][k]     = pa0 + pe0 + deg_s[jl]     * (ph0 + bmk);
        ms_s[jl + 2][k] = pa1 + pe1 + deg_s[jl + 2] * (ph1 + bmk);
    }
    __syncthreads();

    // ---- E: out = h·WuA^T + msum·WuB^T + bu ----
    {
        float o0 = 0, o1 = 0;
        const float4* __restrict__ wap = (const float4*)WuT4 + k;
        const float4* __restrict__ wbp = wap + 32 * 128;                    // dcol = 128+d0
        for (int q = 0; q < 32; ++q) {
            const float4 wa = wap[q * 128];
            const float4 wb = wbp[q * 128];
            const float4 hA = *(const float4*)&h_s[jl][4 * q];
            const float4 hB = *(const float4*)&h_s[jl + 2][4 * q];
            const float4 mA = *(const float4*)&ms_s[jl][4 * q];
            const float4 mB = *(const float4*)&ms_s[jl + 2][4 * q];
            o0 += hA.x * wa.x + hA.y * wa.y + hA.z * wa.z + hA.w * wa.w
                + mA.x * wb.x + mA.y * wb.y + mA.z * wb.z + mA.w * wb.w;
            o1 += hB.x * wa.x + hB.y * wa.y + hB.z * wa.z + hB.w * wa.w
                + mB.x * wb.x + mB.y * wb.y + mB.z * wb.z + mB.w * wb.w;
        }
        const float buk = bu[k];
        out[(size_t)(b * NN + jbase + jl) * DD + k]     = o0 + buk;
        out[(size_t)(b * NN + jbase + jl + 2) * DD + k] = o1 + buk;
    }
}

extern "C" void kernel_launch(void* const* d_in, const int* in_sizes, int n_in,
                              void* d_out, int out_size, void* d_ws, size_t ws_size,
                              hipStream_t stream) {
    const float* h   = (const float*)d_in[0];
    const float* adj = (const float*)d_in[1];
    const float* e   = (const float*)d_in[2];
    const float* Wm  = (const float*)d_in[3];
    const float* bm  = (const float*)d_in[4];
    const float* Wu  = (const float*)d_in[5];
    const float* bu  = (const float*)d_in[6];
    float* out  = (float*)d_out;
    float* WmT4 = (float*)d_ws;                // 384*128 floats
    float* WuT4 = WmT4 + 384 * 128;            // 256*128 floats (320 KB total)

    wtrans_kernel<<<320, 256, 0, stream>>>(Wm, Wu, WmT4, WuT4);
    mpnn_kernel<<<BB * (NN / 4), 256, 0, stream>>>(h, adj, e, WmT4, bm, WuT4, bu, out);
}